// Round 1
// baseline (130.144 us; speedup 1.0000x reference)
//
#include <hip/hip_runtime.h>

typedef unsigned short u16;
typedef __attribute__((ext_vector_type(8))) short bf16x8;
typedef __attribute__((ext_vector_type(4))) float f32x4;
typedef __attribute__((ext_vector_type(4))) unsigned int u32x4;
typedef __attribute__((ext_vector_type(4))) unsigned short u16x4;

#define DEV static __device__ __forceinline__

DEV u16 f2bf(float f) {
  unsigned u = __builtin_bit_cast(unsigned, f);
  u += 0x7FFFu + ((u >> 16) & 1u);
  return (u16)(u >> 16);
}

DEV void load_lds16(const void* g, void* l) {
  __builtin_amdgcn_global_load_lds(
      (const __attribute__((address_space(1))) unsigned int*)g,
      (__attribute__((address_space(3))) unsigned int*)l, 16, 0, 0);
}

// ---------------- prep kernels ----------------

__global__ void k_convert_x(const float* __restrict__ x, u16* __restrict__ xb) {
  int i = (blockIdx.x * 256 + threadIdx.x) * 4;
  f32x4 v = *(const f32x4*)(x + i);
  u16x4 o;
#pragma unroll
  for (int j = 0; j < 4; ++j) o[j] = f2bf(v[j]);
  *(u16x4*)(xb + i) = o;
}

__global__ void k_pack_bias(const float* __restrict__ bq, const float* __restrict__ bk,
                            const float* __restrict__ bv, float* __restrict__ bias) {
  int i = blockIdx.x * 256 + threadIdx.x;  // 0..3071
  float v = (i < 1024) ? bq[i] : (i < 2048) ? bk[i - 1024] : bv[i - 2048];
  bias[i] = v;
}

// W [1024][1024] f32 -> Wt [n][k] bf16
__global__ void k_transpose_w(const float* __restrict__ W, u16* __restrict__ Wt) {
  __shared__ float t[32][33];
  int tx = threadIdx.x, ty = threadIdx.y;
  int c0 = blockIdx.x * 32, r0 = blockIdx.y * 32;
#pragma unroll
  for (int i = 0; i < 4; ++i)
    t[ty + i * 8][tx] = W[(size_t)(r0 + ty + i * 8) * 1024 + c0 + tx];
  __syncthreads();
#pragma unroll
  for (int i = 0; i < 4; ++i)
    Wt[(size_t)(c0 + ty + i * 8) * 1024 + r0 + tx] = f2bf(t[tx][ty + i * 8]);
}

// V slice of qkv [4096][3072] -> vt[(b*16+h)*64+d][s]
__global__ void k_transpose_v(const u16* __restrict__ qkv, u16* __restrict__ vt) {
  __shared__ u16 t[32][33];
  int tx = threadIdx.x, ty = threadIdx.y;
  int s0 = blockIdx.x * 32, d0 = blockIdx.y * 32, bh = blockIdx.z;
  int b = bh >> 4, h = bh & 15;
#pragma unroll
  for (int i = 0; i < 4; ++i)
    t[ty + i * 8][tx] =
        qkv[(size_t)(b * 2048 + s0 + ty + i * 8) * 3072 + 2048 + h * 64 + d0 + tx];
  __syncthreads();
#pragma unroll
  for (int i = 0; i < 4; ++i)
    vt[(size_t)(bh * 64 + d0 + ty + i * 8) * 2048 + s0 + tx] = t[tx][ty + i * 8];
}

// ---------------- GEMM: C[M][ldc] = A[M][1024] * Bt[N][1024]^T + bias ----------------
// 128x128 tile, BK=32, 4 waves (2x2), each wave 64x64 = 4x4 fragments of 16x16x32.

template <typename CT>
__launch_bounds__(256) __global__
void k_gemm_bt(const u16* __restrict__ A, const u16* __restrict__ Bt,
               const float* __restrict__ bias, CT* __restrict__ C, int ldc) {
  __shared__ __align__(16) u16 lA[128 * 32];
  __shared__ __align__(16) u16 lB[128 * 32];
  __shared__ __align__(16) float ep[4][16][68];
  const int tid = threadIdx.x;
  const int w = tid >> 6, lane = tid & 63, g = lane >> 4, n16 = lane & 15;
  const int wm = w >> 1, wn = w & 1;
  const int m0 = blockIdx.y * 128, n0 = blockIdx.x * 128;

  f32x4 acc[4][4] = {};
  for (int k0 = 0; k0 < 1024; k0 += 32) {
    __syncthreads();
#pragma unroll
    for (int r = 0; r < 2; ++r) {
      int c = r * 256 + tid;  // 16B chunk index, 512 chunks per tile
      load_lds16(A + (size_t)(m0 + (c >> 2)) * 1024 + k0 + (c & 3) * 8, &lA[c * 8]);
      load_lds16(Bt + (size_t)(n0 + (c >> 2)) * 1024 + k0 + (c & 3) * 8, &lB[c * 8]);
    }
    __syncthreads();
    bf16x8 af[4], bfr[4];
#pragma unroll
    for (int i = 0; i < 4; ++i)
      af[i] = *(const bf16x8*)&lA[(wm * 64 + i * 16 + n16) * 32 + g * 8];
#pragma unroll
    for (int j = 0; j < 4; ++j)
      bfr[j] = *(const bf16x8*)&lB[(wn * 64 + j * 16 + n16) * 32 + g * 8];
#pragma unroll
    for (int i = 0; i < 4; ++i)
#pragma unroll
      for (int j = 0; j < 4; ++j)
        acc[i][j] = __builtin_amdgcn_mfma_f32_16x16x32_bf16(af[i], bfr[j], acc[i][j], 0, 0, 0);
  }

  // epilogue: per wave, stage 16x64 f32 in LDS then coalesced vector stores
  const int m_base = m0 + wm * 64, n_base = n0 + wn * 64;
#pragma unroll
  for (int i = 0; i < 4; ++i) {
#pragma unroll
    for (int j = 0; j < 4; ++j) {
      float bv = bias[n_base + j * 16 + n16];
#pragma unroll
      for (int jj = 0; jj < 4; ++jj)
        ep[w][g * 4 + jj][j * 16 + n16] = acc[i][j][jj] + bv;
    }
    asm volatile("s_waitcnt lgkmcnt(0)" ::: "memory");
#pragma unroll
    for (int p = 0; p < 4; ++p) {
      int row = p * 4 + g;
      f32x4 v = *(const f32x4*)&ep[w][row][n16 * 4];
      size_t off = (size_t)(m_base + i * 16 + row) * ldc + n_base + n16 * 4;
      if constexpr (sizeof(CT) == 2) {
        u16x4 o;
#pragma unroll
        for (int q = 0; q < 4; ++q) o[q] = f2bf(v[q]);
        *(u16x4*)(C + off) = o;
      } else {
        *(f32x4*)(C + off) = v;
      }
    }
    asm volatile("s_waitcnt lgkmcnt(0)" ::: "memory");
  }
}

// ---------------- banded attention ----------------
// block = (b, h, 64-query tile); 4 waves, wave w owns 16 q-rows.
// full 320-key score row per wave held in registers (20 f32x4).

__launch_bounds__(256) __global__
void k_attn(const u16* __restrict__ qkv, const u16* __restrict__ vt,
            u16* __restrict__ attn) {
  __shared__ __align__(16) u16 Pl[4][16][328];   // P tile per wave (stride 328: 16B-aligned, conflict-light)
  __shared__ __align__(16) u16 Ostg[4][16][64];  // output staging
  const int tid = threadIdx.x;
  const int w = tid >> 6, lane = tid & 63, g = lane >> 4, n16 = lane & 15;
  const int bid = blockIdx.x;
  const int qt = bid & 31, h = (bid >> 5) & 15, b = bid >> 9;
  const int q0 = qt * 64 + w * 16;  // wave's q base
  const int kv0 = qt * 64 - 128;    // block key range start (320 keys)

  // Q fragments (A-operand): rows m = n16, k = d
  const size_t rowQ = (size_t)(b * 2048 + q0 + n16) * 3072 + h * 64;
  bf16x8 qf0 = *(const bf16x8*)(qkv + rowQ + g * 8);
  bf16x8 qf1 = *(const bf16x8*)(qkv + rowQ + 32 + g * 8);

  // scores: C[q_local][key_local] over 20 key subtiles of 16
  f32x4 sv[20];
#pragma unroll
  for (int t = 0; t < 20; ++t) {
    int kr = kv0 + t * 16 + n16;
    int krc = min(max(kr, 0), 2047);
    const u16* kp = qkv + (size_t)(b * 2048 + krc) * 3072 + 1024 + h * 64 + g * 8;
    bf16x8 kf0 = *(const bf16x8*)kp;
    bf16x8 kf1 = *(const bf16x8*)(kp + 32);
    f32x4 s = {0.f, 0.f, 0.f, 0.f};
    s = __builtin_amdgcn_mfma_f32_16x16x32_bf16(qf0, kf0, s, 0, 0, 0);
    s = __builtin_amdgcn_mfma_f32_16x16x32_bf16(qf1, kf1, s, 0, 0, 0);
    sv[t] = s;
  }

  // scale + band mask
  const float scale = 0.03125f;  // 1/sqrt(1024)
#pragma unroll
  for (int t = 0; t < 20; ++t) {
    int k = kv0 + t * 16 + n16;
#pragma unroll
    for (int jj = 0; jj < 4; ++jj) {
      int q = q0 + g * 4 + jj;
      int d = q - k;
      bool ok = (k >= 0) && (k < 2048) && (d <= 128) && (d >= -128);
      sv[t][jj] = ok ? sv[t][jj] * scale : -__builtin_inff();
    }
  }

  // softmax per q-row (row spread over 16 lanes sharing g, x 20 tiles)
#pragma unroll
  for (int jj = 0; jj < 4; ++jj) {
    float mx = -__builtin_inff();
#pragma unroll
    for (int t = 0; t < 20; ++t) mx = fmaxf(mx, sv[t][jj]);
#pragma unroll
    for (int m = 1; m < 16; m <<= 1) mx = fmaxf(mx, __shfl_xor(mx, m));
    float sum = 0.f;
#pragma unroll
    for (int t = 0; t < 20; ++t) {
      float p = __expf(sv[t][jj] - mx);
      sv[t][jj] = p;
      sum += p;
    }
#pragma unroll
    for (int m = 1; m < 16; m <<= 1) sum += __shfl_xor(sum, m);
    float inv = 1.f / sum;
#pragma unroll
    for (int t = 0; t < 20; ++t) sv[t][jj] *= inv;
  }

  // P -> LDS (bf16), D-layout scatter
#pragma unroll
  for (int t = 0; t < 20; ++t)
#pragma unroll
    for (int jj = 0; jj < 4; ++jj)
      Pl[w][g * 4 + jj][t * 16 + n16] = f2bf(sv[t][jj]);
  __syncthreads();

  // PV: O[q_local][d] = sum_k P[q][k] * V[k][d]; V^T gives contiguous-k reads
  const int bh = b * 16 + h;
  f32x4 oacc[4] = {};
#pragma unroll
  for (int st = 0; st < 10; ++st) {
    bf16x8 pf = *(const bf16x8*)&Pl[w][n16][st * 32 + g * 8];
    int kq = kv0 + st * 32 + g * 8;
    int kqc = min(max(kq, 0), 2040);  // clamp: P is exactly 0 on masked slots
#pragma unroll
    for (int dt = 0; dt < 4; ++dt) {
      const u16* vp = vt + (size_t)(bh * 64 + dt * 16 + n16) * 2048 + kqc;
      bf16x8 vf = *(const bf16x8*)vp;
      oacc[dt] = __builtin_amdgcn_mfma_f32_16x16x32_bf16(pf, vf, oacc[dt], 0, 0, 0);
    }
  }

  // stage O per wave, then coalesced 16B stores
#pragma unroll
  for (int dt = 0; dt < 4; ++dt)
#pragma unroll
    for (int jj = 0; jj < 4; ++jj)
      Ostg[w][g * 4 + jj][dt * 16 + n16] = f2bf(oacc[dt][jj]);
  asm volatile("s_waitcnt lgkmcnt(0)" ::: "memory");
#pragma unroll
  for (int p = 0; p < 2; ++p) {
    int fl = p * 512 + lane * 8;  // ushort index into [16][64]
    int row = fl >> 6, col = fl & 63;
    u32x4 v = *(const u32x4*)&Ostg[w][row][col];
    *(u32x4*)(attn + (size_t)(b * 2048 + q0 + row) * 1024 + h * 64 + col) = v;
  }
}

// ---------------- launch ----------------

extern "C" void kernel_launch(void* const* d_in, const int* in_sizes, int n_in,
                              void* d_out, int out_size, void* d_ws, size_t ws_size,
                              hipStream_t stream) {
  const float* x  = (const float*)d_in[0];
  const float* Wq = (const float*)d_in[1];
  const float* bq = (const float*)d_in[2];
  const float* Wk = (const float*)d_in[3];
  const float* bk = (const float*)d_in[4];
  const float* Wv = (const float*)d_in[5];
  const float* bv = (const float*)d_in[6];
  const float* Wo = (const float*)d_in[7];
  const float* bo = (const float*)d_in[8];

  char* ws = (char*)d_ws;
  const size_t MB = 1ull << 20;
  u16*   xb    = (u16*)(ws + 0);         // 8 MB   (dead after QKV GEMM)
  u16*   wtqkv = (u16*)(ws + 8 * MB);    // 6 MB
  u16*   wto   = (u16*)(ws + 14 * MB);   // 2 MB
  float* bias  = (float*)(ws + 16 * MB); // 12 KB
  u16*   qkvb  = (u16*)(ws + 17 * MB);   // 24 MB
  u16*   vtb   = (u16*)(ws + 41 * MB);   // 8 MB
  u16*   attnb = (u16*)(ws + 0);         // reuse xb's 8 MB

  dim3 tb(32, 8);
  k_convert_x<<<4096, 256, 0, stream>>>(x, xb);
  k_pack_bias<<<12, 256, 0, stream>>>(bq, bk, bv, bias);
  k_transpose_w<<<dim3(32, 32), tb, 0, stream>>>(Wq, wtqkv);
  k_transpose_w<<<dim3(32, 32), tb, 0, stream>>>(Wk, wtqkv + 1024 * 1024);
  k_transpose_w<<<dim3(32, 32), tb, 0, stream>>>(Wv, wtqkv + 2 * 1024 * 1024);
  k_transpose_w<<<dim3(32, 32), tb, 0, stream>>>(Wo, wto);

  k_gemm_bt<u16><<<dim3(24, 32), 256, 0, stream>>>(xb, wtqkv, bias, qkvb, 3072);
  k_transpose_v<<<dim3(64, 2, 32), tb, 0, stream>>>(qkvb, vtb);
  k_attn<<<1024, 256, 0, stream>>>(qkvb, vtb, attnb);
  k_gemm_bt<float><<<dim3(8, 32), 256, 0, stream>>>(attnb, wto, bo, (float*)d_out, 1024);
}

// Round 2
// 122.934 us; speedup vs baseline: 1.0586x; 1.0586x over previous
//
#include <hip/hip_runtime.h>

typedef unsigned short u16;
typedef unsigned int u32;
typedef __attribute__((ext_vector_type(8))) short bf16x8;
typedef __attribute__((ext_vector_type(4))) float f32x4;
typedef __attribute__((ext_vector_type(4))) unsigned int u32x4;
typedef __attribute__((ext_vector_type(4))) unsigned short u16x4;

#define DEV static __device__ __forceinline__

DEV u16 f2bf(float f) {
  unsigned u = __builtin_bit_cast(unsigned, f);
  u += 0x7FFFu + ((u >> 16) & 1u);
  return (u16)(u >> 16);
}

DEV u32 cvt_pk_bf16(float lo, float hi) {
  u32 d;
  asm("v_cvt_pk_bf16_f32 %0, %1, %2" : "=v"(d) : "v"(lo), "v"(hi));
  return d;
}

DEV void load_lds16(const void* g, void* l) {
  __builtin_amdgcn_global_load_lds(
      (const __attribute__((address_space(1))) unsigned int*)g,
      (__attribute__((address_space(3))) unsigned int*)l, 16, 0, 0);
}

// ---------------- prep kernels ----------------

__global__ void k_convert_x(const float* __restrict__ x, u16* __restrict__ xb) {
  int i = (blockIdx.x * 256 + threadIdx.x) * 4;
  f32x4 v = *(const f32x4*)(x + i);
  u16x4 o;
#pragma unroll
  for (int j = 0; j < 4; ++j) o[j] = f2bf(v[j]);
  *(u16x4*)(xb + i) = o;
}

__global__ void k_pack_bias(const float* __restrict__ bq, const float* __restrict__ bk,
                            const float* __restrict__ bv, float* __restrict__ bias) {
  int i = blockIdx.x * 256 + threadIdx.x;  // 0..3071
  float v = (i < 1024) ? bq[i] : (i < 2048) ? bk[i - 1024] : bv[i - 2048];
  bias[i] = v;
}

// W [1024][1024] f32 -> Wt [n][k] bf16
__global__ void k_transpose_w(const float* __restrict__ W, u16* __restrict__ Wt) {
  __shared__ float t[32][33];
  int tx = threadIdx.x, ty = threadIdx.y;
  int c0 = blockIdx.x * 32, r0 = blockIdx.y * 32;
#pragma unroll
  for (int i = 0; i < 4; ++i)
    t[ty + i * 8][tx] = W[(size_t)(r0 + ty + i * 8) * 1024 + c0 + tx];
  __syncthreads();
#pragma unroll
  for (int i = 0; i < 4; ++i)
    Wt[(size_t)(c0 + ty + i * 8) * 1024 + r0 + tx] = f2bf(t[tx][ty + i * 8]);
}

// V slice of qkv [4096][3072] -> vt[(b*16+h)*64+d][s]
__global__ void k_transpose_v(const u16* __restrict__ qkv, u16* __restrict__ vt) {
  __shared__ u16 t[32][33];
  int tx = threadIdx.x, ty = threadIdx.y;
  int s0 = blockIdx.x * 32, d0 = blockIdx.y * 32, bh = blockIdx.z;
  int b = bh >> 4, h = bh & 15;
#pragma unroll
  for (int i = 0; i < 4; ++i)
    t[ty + i * 8][tx] =
        qkv[(size_t)(b * 2048 + s0 + ty + i * 8) * 3072 + 2048 + h * 64 + d0 + tx];
  __syncthreads();
#pragma unroll
  for (int i = 0; i < 4; ++i)
    vt[(size_t)(bh * 64 + d0 + ty + i * 8) * 2048 + s0 + tx] = t[tx][ty + i * 8];
}

// ---------------- GEMM: C[M][ldc] = A[M][1024] * Bt[N][1024]^T + bias ----------------
// 128x128 tile, BK=32, 4 waves (2x2), each wave 64x64 = 4x4 fragments of 16x16x32.

template <typename CT>
__launch_bounds__(256) __global__
void k_gemm_bt(const u16* __restrict__ A, const u16* __restrict__ Bt,
               const float* __restrict__ bias, CT* __restrict__ C, int ldc) {
  __shared__ __align__(16) u16 lA[128 * 32];
  __shared__ __align__(16) u16 lB[128 * 32];
  __shared__ __align__(16) float ep[4][16][68];
  const int tid = threadIdx.x;
  const int w = tid >> 6, lane = tid & 63, g = lane >> 4, n16 = lane & 15;
  const int wm = w >> 1, wn = w & 1;
  const int m0 = blockIdx.y * 128, n0 = blockIdx.x * 128;

  f32x4 acc[4][4] = {};
  for (int k0 = 0; k0 < 1024; k0 += 32) {
    __syncthreads();
#pragma unroll
    for (int r = 0; r < 2; ++r) {
      int c = r * 256 + tid;  // 16B chunk index, 512 chunks per tile
      load_lds16(A + (size_t)(m0 + (c >> 2)) * 1024 + k0 + (c & 3) * 8, &lA[c * 8]);
      load_lds16(Bt + (size_t)(n0 + (c >> 2)) * 1024 + k0 + (c & 3) * 8, &lB[c * 8]);
    }
    __syncthreads();
    bf16x8 af[4], bfr[4];
#pragma unroll
    for (int i = 0; i < 4; ++i)
      af[i] = *(const bf16x8*)&lA[(wm * 64 + i * 16 + n16) * 32 + g * 8];
#pragma unroll
    for (int j = 0; j < 4; ++j)
      bfr[j] = *(const bf16x8*)&lB[(wn * 64 + j * 16 + n16) * 32 + g * 8];
#pragma unroll
    for (int i = 0; i < 4; ++i)
#pragma unroll
      for (int j = 0; j < 4; ++j)
        acc[i][j] = __builtin_amdgcn_mfma_f32_16x16x32_bf16(af[i], bfr[j], acc[i][j], 0, 0, 0);
  }

  // epilogue: per wave, stage 16x64 f32 in LDS then coalesced vector stores
  const int m_base = m0 + wm * 64, n_base = n0 + wn * 64;
#pragma unroll
  for (int i = 0; i < 4; ++i) {
#pragma unroll
    for (int j = 0; j < 4; ++j) {
      float bv = bias[n_base + j * 16 + n16];
#pragma unroll
      for (int jj = 0; jj < 4; ++jj)
        ep[w][g * 4 + jj][j * 16 + n16] = acc[i][j][jj] + bv;
    }
    asm volatile("s_waitcnt lgkmcnt(0)" ::: "memory");
#pragma unroll
    for (int p = 0; p < 4; ++p) {
      int row = p * 4 + g;
      f32x4 v = *(const f32x4*)&ep[w][row][n16 * 4];
      size_t off = (size_t)(m_base + i * 16 + row) * ldc + n_base + n16 * 4;
      if constexpr (sizeof(CT) == 2) {
        u16x4 o;
#pragma unroll
        for (int q = 0; q < 4; ++q) o[q] = f2bf(v[q]);
        *(u16x4*)(C + off) = o;
      } else {
        *(f32x4*)(C + off) = v;
      }
    }
    asm volatile("s_waitcnt lgkmcnt(0)" ::: "memory");
  }
}

// ---------------- banded attention (swapped-operand, zero-LDS P path) ----------------
// block = (b, h, 64-query tile); 4 waves, wave w owns 16 q-rows, fully independent.
// QK^T computed as mfma(K, Q): lane (g,n16) holds scores for query q0+n16 only.
// Key->MFMA-row map: key = kv0 + 32*(t>>1) + 8*(m>>2) + 4*(t&1) + (m&3); with m=4g+jj
// a lane owns keys 32s+8g+{0..7} across tile pair (2s,2s+1) == exactly the PV A-frag.

__launch_bounds__(256, 4) __global__
void k_attn(const u16* __restrict__ qkv, const u16* __restrict__ vt,
            u16* __restrict__ attn) {
  __shared__ __align__(16) u16 Ostg[4][16][64];  // per-wave output staging (8 KB)
  const int tid = threadIdx.x;
  const int w = tid >> 6, lane = tid & 63, g = lane >> 4, n16 = lane & 15;
  const int bid = blockIdx.x;
  const int qt = bid & 31, h = (bid >> 5) & 15, b = bid >> 9;
  const int q0 = qt * 64 + w * 16;  // wave's q base
  const int kv0 = q0 - 128;         // wave-local key window: 18 tiles = 288 keys
  const int q = q0 + n16;           // this lane's query row

  // Q fragment (B-operand): rows n = n16 (query), k = d
  const size_t rowQ = (size_t)(b * 2048 + q) * 3072 + h * 64;
  bf16x8 qf0 = *(const bf16x8*)(qkv + rowQ + g * 8);
  bf16x8 qf1 = *(const bf16x8*)(qkv + rowQ + 32 + g * 8);

  // scores: sv[t][jj] = S[key(t, 4g+jj)][q]
  const int kbase = 8 * (n16 >> 2) + (n16 & 3);
  f32x4 sv[18];
#pragma unroll
  for (int t = 0; t < 18; ++t) {
    int kr = kv0 + 32 * (t >> 1) + 4 * (t & 1) + kbase;
    int krc = min(max(kr, 0), 2047);
    const u16* kp = qkv + (size_t)(b * 2048 + krc) * 3072 + 1024 + h * 64 + g * 8;
    bf16x8 kf0 = *(const bf16x8*)kp;
    bf16x8 kf1 = *(const bf16x8*)(kp + 32);
    f32x4 s = {0.f, 0.f, 0.f, 0.f};
    s = __builtin_amdgcn_mfma_f32_16x16x32_bf16(kf0, qf0, s, 0, 0, 0);
    s = __builtin_amdgcn_mfma_f32_16x16x32_bf16(kf1, qf1, s, 0, 0, 0);
    sv[t] = s;
  }

  // band mask (scale folded into exp2 below)
  const float NEG = -__builtin_inff();
#pragma unroll
  for (int t = 0; t < 18; ++t) {
    int kb = kv0 + 32 * (t >> 1) + 4 * (t & 1) + 8 * g;
#pragma unroll
    for (int jj = 0; jj < 4; ++jj) {
      int k = kb + jj;
      bool ok = ((unsigned)k < 2048u) && ((unsigned)(q - k + 128) <= 256u);
      sv[t][jj] = ok ? sv[t][jj] : NEG;
    }
  }

  // softmax for query q: in-lane max/sum + 2-shfl reduce over the 4 g-lanes
  float mx = NEG;
#pragma unroll
  for (int t = 0; t < 18; ++t)
    mx = fmaxf(mx, fmaxf(fmaxf(sv[t][0], sv[t][1]), fmaxf(sv[t][2], sv[t][3])));
  mx = fmaxf(mx, __shfl_xor(mx, 16));
  mx = fmaxf(mx, __shfl_xor(mx, 32));

  const float c = 0.04508422017f;  // log2(e) / sqrt(1024)
  const float nmc = -mx * c;
  float sum = 0.f;
#pragma unroll
  for (int t = 0; t < 18; ++t)
#pragma unroll
    for (int jj = 0; jj < 4; ++jj) {
      float p = exp2f(fmaf(sv[t][jj], c, nmc));  // 0 on masked slots
      sv[t][jj] = p;
      sum += p;
    }
  sum += __shfl_xor(sum, 16);
  sum += __shfl_xor(sum, 32);
  const float inv = 1.f / sum;

  // PV: O[q][d] = (sum_k p[k] V[k][d]) * inv ; P already lane-local in A-frag order
  const int bh = b * 16 + h;
  f32x4 oacc[4] = {};
#pragma unroll
  for (int s = 0; s < 9; ++s) {
    union { u32 u[4]; bf16x8 v; } paf;
    paf.u[0] = cvt_pk_bf16(sv[2 * s][0], sv[2 * s][1]);
    paf.u[1] = cvt_pk_bf16(sv[2 * s][2], sv[2 * s][3]);
    paf.u[2] = cvt_pk_bf16(sv[2 * s + 1][0], sv[2 * s + 1][1]);
    paf.u[3] = cvt_pk_bf16(sv[2 * s + 1][2], sv[2 * s + 1][3]);
    int kq = kv0 + s * 32 + g * 8;           // multiple of 8
    int kqc = min(max(kq, 0), 2040);         // clamp ok: p==0 on masked slots
#pragma unroll
    for (int dt = 0; dt < 4; ++dt) {
      const u16* vp = vt + (size_t)(bh * 64 + dt * 16 + n16) * 2048 + kqc;
      bf16x8 vf = *(const bf16x8*)vp;
      oacc[dt] = __builtin_amdgcn_mfma_f32_16x16x32_bf16(paf.v, vf, oacc[dt], 0, 0, 0);
    }
  }

  // normalize per output row (q-sub = 4g+jj): fetch inv from owning lane
  float rs[4];
#pragma unroll
  for (int jj = 0; jj < 4; ++jj) rs[jj] = __shfl(inv, 4 * g + jj);

  // stage O per wave, then coalesced 16B stores
#pragma unroll
  for (int dt = 0; dt < 4; ++dt)
#pragma unroll
    for (int jj = 0; jj < 4; ++jj)
      Ostg[w][g * 4 + jj][dt * 16 + n16] = f2bf(oacc[dt][jj] * rs[jj]);
  asm volatile("s_waitcnt lgkmcnt(0)" ::: "memory");
#pragma unroll
  for (int p = 0; p < 2; ++p) {
    int fl = p * 512 + lane * 8;  // ushort index into [16][64]
    int row = fl >> 6, col = fl & 63;
    u32x4 v = *(const u32x4*)&Ostg[w][row][col];
    *(u32x4*)(attn + (size_t)(b * 2048 + q0 + row) * 1024 + h * 64 + col) = v;
  }
}

// ---------------- launch ----------------

extern "C" void kernel_launch(void* const* d_in, const int* in_sizes, int n_in,
                              void* d_out, int out_size, void* d_ws, size_t ws_size,
                              hipStream_t stream) {
  const float* x  = (const float*)d_in[0];
  const float* Wq = (const float*)d_in[1];
  const float* bq = (const float*)d_in[2];
  const float* Wk = (const float*)d_in[3];
  const float* bk = (const float*)d_in[4];
  const float* Wv = (const float*)d_in[5];
  const float* bv = (const float*)d_in[6];
  const float* Wo = (const float*)d_in[7];
  const float* bo = (const float*)d_in[8];

  char* ws = (char*)d_ws;
  const size_t MB = 1ull << 20;
  u16*   xb    = (u16*)(ws + 0);         // 8 MB   (dead after QKV GEMM)
  u16*   wtqkv = (u16*)(ws + 8 * MB);    // 6 MB
  u16*   wto   = (u16*)(ws + 14 * MB);   // 2 MB
  float* bias  = (float*)(ws + 16 * MB); // 12 KB
  u16*   qkvb  = (u16*)(ws + 17 * MB);   // 24 MB
  u16*   vtb   = (u16*)(ws + 41 * MB);   // 8 MB
  u16*   attnb = (u16*)(ws + 0);         // reuse xb's 8 MB

  dim3 tb(32, 8);
  k_convert_x<<<4096, 256, 0, stream>>>(x, xb);
  k_pack_bias<<<12, 256, 0, stream>>>(bq, bk, bv, bias);
  k_transpose_w<<<dim3(32, 32), tb, 0, stream>>>(Wq, wtqkv);
  k_transpose_w<<<dim3(32, 32), tb, 0, stream>>>(Wk, wtqkv + 1024 * 1024);
  k_transpose_w<<<dim3(32, 32), tb, 0, stream>>>(Wv, wtqkv + 2 * 1024 * 1024);
  k_transpose_w<<<dim3(32, 32), tb, 0, stream>>>(Wo, wto);

  k_gemm_bt<u16><<<dim3(24, 32), 256, 0, stream>>>(xb, wtqkv, bias, qkvb, 3072);
  k_transpose_v<<<dim3(64, 2, 32), tb, 0, stream>>>(qkvb, vtb);
  k_attn<<<1024, 256, 0, stream>>>(qkvb, vtb, attnb);
  k_gemm_bt<float><<<dim3(8, 32), 256, 0, stream>>>(attnb, wto, bo, (float*)d_out, 1024);
}

// Round 3
// 101.434 us; speedup vs baseline: 1.2830x; 1.2120x over previous
//
#include <hip/hip_runtime.h>

typedef unsigned short u16;
typedef unsigned int u32;
typedef __attribute__((ext_vector_type(8))) short bf16x8;
typedef __attribute__((ext_vector_type(4))) float f32x4;
typedef __attribute__((ext_vector_type(4))) unsigned int u32x4;
typedef __attribute__((ext_vector_type(4))) unsigned short u16x4;

#define DEV static __device__ __forceinline__

DEV u16 f2bf(float f) {
  unsigned u = __builtin_bit_cast(unsigned, f);
  u += 0x7FFFu + ((u >> 16) & 1u);
  return (u16)(u >> 16);
}

DEV u32 cvt_pk_bf16(float lo, float hi) {
  u32 d;
  asm("v_cvt_pk_bf16_f32 %0, %1, %2" : "=v"(d) : "v"(lo), "v"(hi));
  return d;
}

DEV void load_lds16(const void* g, void* l) {
  __builtin_amdgcn_global_load_lds(
      (const __attribute__((address_space(1))) unsigned int*)g,
      (__attribute__((address_space(3))) unsigned int*)l, 16, 0, 0);
}

// ---------------- prep kernels ----------------

__global__ void k_convert_x(const float* __restrict__ x, u16* __restrict__ xb) {
  int i = (blockIdx.x * 256 + threadIdx.x) * 4;
  f32x4 v = *(const f32x4*)(x + i);
  u16x4 o;
#pragma unroll
  for (int j = 0; j < 4; ++j) o[j] = f2bf(v[j]);
  *(u16x4*)(xb + i) = o;
}

__global__ void k_pack_bias(const float* __restrict__ bq, const float* __restrict__ bk,
                            const float* __restrict__ bv, float* __restrict__ bias) {
  int i = blockIdx.x * 256 + threadIdx.x;  // 0..3071
  float v = (i < 1024) ? bq[i] : (i < 2048) ? bk[i - 1024] : bv[i - 2048];
  bias[i] = v;
}

// W [1024][1024] f32 -> Wt [n][k] bf16
__global__ void k_transpose_w(const float* __restrict__ W, u16* __restrict__ Wt) {
  __shared__ float t[32][33];
  int tx = threadIdx.x, ty = threadIdx.y;
  int c0 = blockIdx.x * 32, r0 = blockIdx.y * 32;
#pragma unroll
  for (int i = 0; i < 4; ++i)
    t[ty + i * 8][tx] = W[(size_t)(r0 + ty + i * 8) * 1024 + c0 + tx];
  __syncthreads();
#pragma unroll
  for (int i = 0; i < 4; ++i)
    Wt[(size_t)(c0 + ty + i * 8) * 1024 + r0 + tx] = f2bf(t[tx][ty + i * 8]);
}

// V slice of qkv [4096][3072] -> vt[(b*16+h)*64+d][s]
__global__ void k_transpose_v(const u16* __restrict__ qkv, u16* __restrict__ vt) {
  __shared__ u16 t[32][33];
  int tx = threadIdx.x, ty = threadIdx.y;
  int s0 = blockIdx.x * 32, d0 = blockIdx.y * 32, bh = blockIdx.z;
  int b = bh >> 4, h = bh & 15;
#pragma unroll
  for (int i = 0; i < 4; ++i)
    t[ty + i * 8][tx] =
        qkv[(size_t)(b * 2048 + s0 + ty + i * 8) * 3072 + 2048 + h * 64 + d0 + tx];
  __syncthreads();
#pragma unroll
  for (int i = 0; i < 4; ++i)
    vt[(size_t)(bh * 64 + d0 + ty + i * 8) * 2048 + s0 + tx] = t[tx][ty + i * 8];
}

// ---------------- GEMM: C[M][ldc] = A[M][1024] * Bt[N][1024]^T + bias ----------------

template <typename CT>
__launch_bounds__(256) __global__
void k_gemm_bt(const u16* __restrict__ A, const u16* __restrict__ Bt,
               const float* __restrict__ bias, CT* __restrict__ C, int ldc) {
  __shared__ __align__(16) u16 lA[128 * 32];
  __shared__ __align__(16) u16 lB[128 * 32];
  __shared__ __align__(16) float ep[4][16][68];
  const int tid = threadIdx.x;
  const int w = tid >> 6, lane = tid & 63, g = lane >> 4, n16 = lane & 15;
  const int wm = w >> 1, wn = w & 1;
  const int m0 = blockIdx.y * 128, n0 = blockIdx.x * 128;

  f32x4 acc[4][4] = {};
  for (int k0 = 0; k0 < 1024; k0 += 32) {
    __syncthreads();
#pragma unroll
    for (int r = 0; r < 2; ++r) {
      int c = r * 256 + tid;
      load_lds16(A + (size_t)(m0 + (c >> 2)) * 1024 + k0 + (c & 3) * 8, &lA[c * 8]);
      load_lds16(Bt + (size_t)(n0 + (c >> 2)) * 1024 + k0 + (c & 3) * 8, &lB[c * 8]);
    }
    __syncthreads();
    bf16x8 af[4], bfr[4];
#pragma unroll
    for (int i = 0; i < 4; ++i)
      af[i] = *(const bf16x8*)&lA[(wm * 64 + i * 16 + n16) * 32 + g * 8];
#pragma unroll
    for (int j = 0; j < 4; ++j)
      bfr[j] = *(const bf16x8*)&lB[(wn * 64 + j * 16 + n16) * 32 + g * 8];
#pragma unroll
    for (int i = 0; i < 4; ++i)
#pragma unroll
      for (int j = 0; j < 4; ++j)
        acc[i][j] = __builtin_amdgcn_mfma_f32_16x16x32_bf16(af[i], bfr[j], acc[i][j], 0, 0, 0);
  }

  const int m_base = m0 + wm * 64, n_base = n0 + wn * 64;
#pragma unroll
  for (int i = 0; i < 4; ++i) {
#pragma unroll
    for (int j = 0; j < 4; ++j) {
      float bv = bias[n_base + j * 16 + n16];
#pragma unroll
      for (int jj = 0; jj < 4; ++jj)
        ep[w][g * 4 + jj][j * 16 + n16] = acc[i][j][jj] + bv;
    }
    asm volatile("s_waitcnt lgkmcnt(0)" ::: "memory");
#pragma unroll
    for (int p = 0; p < 4; ++p) {
      int row = p * 4 + g;
      f32x4 v = *(const f32x4*)&ep[w][row][n16 * 4];
      size_t off = (size_t)(m_base + i * 16 + row) * ldc + n_base + n16 * 4;
      if constexpr (sizeof(CT) == 2) {
        u16x4 o;
#pragma unroll
        for (int q = 0; q < 4; ++q) o[q] = f2bf(v[q]);
        *(u16x4*)(C + off) = o;
      } else {
        *(f32x4*)(C + off) = v;
      }
    }
    asm volatile("s_waitcnt lgkmcnt(0)" ::: "memory");
  }
}

// ---------------- banded attention (block-level LDS staging, phased K->V) ----------------
// block = (b, h, 64-query tile); 4 waves. Staged window = [q0b-128, q0b+192) = 320 keys.
// Phase 1: K[320][64] in LDS (40KB), XOR-swizzled cc^=(r&7) via per-lane global src.
// Phase 2: same buffer becomes V^T[64][320] (40 chunks/row, same swizzle).
// Per-wave scores stay in registers (swapped-operand QK^T, P lands in PV A-frag order).

__launch_bounds__(256, 3) __global__
void k_attn(const u16* __restrict__ qkv, const u16* __restrict__ vt,
            u16* __restrict__ attn) {
  __shared__ __align__(16) u16 KV[20480];        // 40KB: K then V^T
  __shared__ __align__(16) u16 Ostg[4][16][64];  // 8KB output staging
  const int tid = threadIdx.x;
  const int w = tid >> 6, lane = tid & 63, g = lane >> 4, n16 = lane & 15;
  // XCD-bijective remap: consecutive logical blocks (same (b,h), adjacent qt) share an XCD
  const int bid = (blockIdx.x & 7) * 128 + (blockIdx.x >> 3);
  const int qt = bid & 31, h = (bid >> 5) & 15, b = bid >> 9;
  const int q0b = qt * 64;
  const int kvb = q0b - 128;        // block window base (multiple of 8... of 64)
  const int q0 = q0b + w * 16;      // wave's q base
  const int kv0 = q0 - 128;         // wave window base (absolute)
  const int q = q0 + n16;           // this lane's query row
  const int bh = b * 16 + h;

  // ---- stage K: LDS chunk (r, cc) holds K[kvb+r][(cc^(r&7))*8 .. +8)
  {
    const u16* kpart = qkv + (size_t)b * 2048 * 3072 + 1024 + h * 64;
#pragma unroll
    for (int i = 0; i < 10; ++i) {
      int c = i * 256 + tid;
      int r = c >> 3, cc = c & 7;
      int srcr = min(max(kvb + r, 0), 2047);
      load_lds16(kpart + (size_t)srcr * 3072 + (cc ^ (r & 7)) * 8, &KV[c * 8]);
    }
  }

  // Q fragment (B-operand) from global, overlaps staging
  const size_t rowQ = (size_t)(b * 2048 + q) * 3072 + h * 64;
  bf16x8 qf0 = *(const bf16x8*)(qkv + rowQ + g * 8);
  bf16x8 qf1 = *(const bf16x8*)(qkv + rowQ + 32 + g * 8);
  __syncthreads();

  // ---- QK^T from LDS: sv[t][jj] = S[key][q], key = kv0+32(t>>1)+4(t&1)+8g+jj (A-frag order)
  const int kbase = 8 * (n16 >> 2) + (n16 & 3);
  const int wrel = 16 * w;
  f32x4 sv[18];
#pragma unroll
  for (int t = 0; t < 18; ++t) {
    int kr = wrel + 32 * (t >> 1) + 4 * (t & 1) + kbase;  // block-relative row
    int krl = min(kr, 319);                               // tail rows are masked
    int p = krl & 7;
    const u16* kp = &KV[krl * 64];
    bf16x8 kf0 = *(const bf16x8*)(kp + (g ^ p) * 8);
    bf16x8 kf1 = *(const bf16x8*)(kp + ((g + 4) ^ p) * 8);
    f32x4 s = {0.f, 0.f, 0.f, 0.f};
    s = __builtin_amdgcn_mfma_f32_16x16x32_bf16(kf0, qf0, s, 0, 0, 0);
    s = __builtin_amdgcn_mfma_f32_16x16x32_bf16(kf1, qf1, s, 0, 0, 0);
    sv[t] = s;
  }
  __syncthreads();  // all waves done reading K region

  // ---- stage V^T into same buffer (async); softmax below hides the latency
  {
    const u16* vpart = vt + (size_t)bh * 64 * 2048;
#pragma unroll
    for (int i = 0; i < 10; ++i) {
      int c = i * 256 + tid;
      int d = c / 40, cc = c - d * 40;
      int j = cc ^ (d & 7);
      int srck = min(max(kvb + j * 8, 0), 2040);
      load_lds16(vpart + (size_t)d * 2048 + srck, &KV[c * 8]);
    }
  }

  // ---- band mask
  const float NEG = -__builtin_inff();
#pragma unroll
  for (int t = 0; t < 18; ++t) {
    int kb = kv0 + 32 * (t >> 1) + 4 * (t & 1) + 8 * g;
#pragma unroll
    for (int jj = 0; jj < 4; ++jj) {
      int k = kb + jj;
      bool ok = ((unsigned)k < 2048u) && ((unsigned)(q - k + 128) <= 256u);
      sv[t][jj] = ok ? sv[t][jj] : NEG;
    }
  }

  // ---- softmax for query q (in-lane + 2 shfls over the 4 g-lanes)
  float mx = NEG;
#pragma unroll
  for (int t = 0; t < 18; ++t)
    mx = fmaxf(mx, fmaxf(fmaxf(sv[t][0], sv[t][1]), fmaxf(sv[t][2], sv[t][3])));
  mx = fmaxf(mx, __shfl_xor(mx, 16));
  mx = fmaxf(mx, __shfl_xor(mx, 32));

  const float c = 0.04508422017f;  // log2(e) / sqrt(1024)
  const float nmc = -mx * c;
  float sum = 0.f;
#pragma unroll
  for (int t = 0; t < 18; ++t)
#pragma unroll
    for (int jj = 0; jj < 4; ++jj) {
      float p = exp2f(fmaf(sv[t][jj], c, nmc));  // 0 on masked slots
      sv[t][jj] = p;
      sum += p;
    }
  sum += __shfl_xor(sum, 16);
  sum += __shfl_xor(sum, 32);
  const float inv = 1.f / sum;

  __syncthreads();  // V^T staged (barrier drains vmcnt) and all waves past mask/softmax

  // ---- PV from LDS V^T; P already lane-local in A-frag order
  f32x4 oacc[4] = {};
#pragma unroll
  for (int s = 0; s < 9; ++s) {
    union { u32 u[4]; bf16x8 v; } paf;
    paf.u[0] = cvt_pk_bf16(sv[2 * s][0], sv[2 * s][1]);
    paf.u[1] = cvt_pk_bf16(sv[2 * s][2], sv[2 * s][3]);
    paf.u[2] = cvt_pk_bf16(sv[2 * s + 1][0], sv[2 * s + 1][1]);
    paf.u[3] = cvt_pk_bf16(sv[2 * s + 1][2], sv[2 * s + 1][3]);
    int jc = min(2 * w + 4 * s + g, 39);  // V^T source chunk; tail has P==0
#pragma unroll
    for (int dt = 0; dt < 4; ++dt) {
      int d = dt * 16 + n16;
      bf16x8 vf = *(const bf16x8*)&KV[d * 320 + (jc ^ (d & 7)) * 8];
      oacc[dt] = __builtin_amdgcn_mfma_f32_16x16x32_bf16(paf.v, vf, oacc[dt], 0, 0, 0);
    }
  }

  // normalize per output row (q-sub = 4g+jj)
  float rs[4];
#pragma unroll
  for (int jj = 0; jj < 4; ++jj) rs[jj] = __shfl(inv, 4 * g + jj);

  // stage O per wave, then coalesced 16B stores
#pragma unroll
  for (int dt = 0; dt < 4; ++dt)
#pragma unroll
    for (int jj = 0; jj < 4; ++jj)
      Ostg[w][g * 4 + jj][dt * 16 + n16] = f2bf(oacc[dt][jj] * rs[jj]);
  asm volatile("s_waitcnt lgkmcnt(0)" ::: "memory");
#pragma unroll
  for (int p = 0; p < 2; ++p) {
    int fl = p * 512 + lane * 8;
    int row = fl >> 6, col = fl & 63;
    u32x4 v = *(const u32x4*)&Ostg[w][row][col];
    *(u32x4*)(attn + (size_t)(b * 2048 + q0 + row) * 1024 + h * 64 + col) = v;
  }
}

// ---------------- launch ----------------

extern "C" void kernel_launch(void* const* d_in, const int* in_sizes, int n_in,
                              void* d_out, int out_size, void* d_ws, size_t ws_size,
                              hipStream_t stream) {
  const float* x  = (const float*)d_in[0];
  const float* Wq = (const float*)d_in[1];
  const float* bq = (const float*)d_in[2];
  const float* Wk = (const float*)d_in[3];
  const float* bk = (const float*)d_in[4];
  const float* Wv = (const float*)d_in[5];
  const float* bv = (const float*)d_in[6];
  const float* Wo = (const float*)d_in[7];
  const float* bo = (const float*)d_in[8];

  char* ws = (char*)d_ws;
  const size_t MB = 1ull << 20;
  u16*   xb    = (u16*)(ws + 0);         // 8 MB   (dead after QKV GEMM)
  u16*   wtqkv = (u16*)(ws + 8 * MB);    // 6 MB
  u16*   wto   = (u16*)(ws + 14 * MB);   // 2 MB
  float* bias  = (float*)(ws + 16 * MB); // 12 KB
  u16*   qkvb  = (u16*)(ws + 17 * MB);   // 24 MB
  u16*   vtb   = (u16*)(ws + 41 * MB);   // 8 MB
  u16*   attnb = (u16*)(ws + 0);         // reuse xb's 8 MB

  dim3 tb(32, 8);
  k_convert_x<<<4096, 256, 0, stream>>>(x, xb);
  k_pack_bias<<<12, 256, 0, stream>>>(bq, bk, bv, bias);
  k_transpose_w<<<dim3(32, 32), tb, 0, stream>>>(Wq, wtqkv);
  k_transpose_w<<<dim3(32, 32), tb, 0, stream>>>(Wk, wtqkv + 1024 * 1024);
  k_transpose_w<<<dim3(32, 32), tb, 0, stream>>>(Wv, wtqkv + 2 * 1024 * 1024);
  k_transpose_w<<<dim3(32, 32), tb, 0, stream>>>(Wo, wto);

  k_gemm_bt<u16><<<dim3(24, 32), 256, 0, stream>>>(xb, wtqkv, bias, qkvb, 3072);
  k_transpose_v<<<dim3(64, 2, 32), tb, 0, stream>>>(qkvb, vtb);
  k_attn<<<1024, 256, 0, stream>>>(qkvb, vtb, attnb);
  k_gemm_bt<float><<<dim3(8, 32), 256, 0, stream>>>(attnb, wto, bo, (float*)d_out, 1024);
}

// Round 4
// 89.751 us; speedup vs baseline: 1.4501x; 1.1302x over previous
//
#include <hip/hip_runtime.h>

typedef unsigned short u16;
typedef unsigned int u32;
typedef __attribute__((ext_vector_type(8))) short bf16x8;
typedef __attribute__((ext_vector_type(4))) float f32x4;
typedef __attribute__((ext_vector_type(4))) unsigned int u32x4;
typedef __attribute__((ext_vector_type(4))) unsigned short u16x4;

#define DEV static __device__ __forceinline__

DEV u16 f2bf(float f) {
  unsigned u = __builtin_bit_cast(unsigned, f);
  u += 0x7FFFu + ((u >> 16) & 1u);
  return (u16)(u >> 16);
}

DEV u32 cvt_pk_bf16(float lo, float hi) {
  u32 d;
  asm("v_cvt_pk_bf16_f32 %0, %1, %2" : "=v"(d) : "v"(lo), "v"(hi));
  return d;
}

DEV void load_lds16(const void* g, void* l) {
  __builtin_amdgcn_global_load_lds(
      (const __attribute__((address_space(1))) unsigned int*)g,
      (__attribute__((address_space(3))) unsigned int*)l, 16, 0, 0);
}

// ---------------- fused prep ----------------
// bid [0,4096):      W transpose (4 weights x 1024 blocks of 32x32)
// bid [4096,8192):   x f32 -> bf16
// bid [8192,8204):   bias pack (q,k,v)

__global__ void k_prep(const float* __restrict__ x,
                       const float* __restrict__ bq, const float* __restrict__ bk,
                       const float* __restrict__ bv,
                       const float* __restrict__ Wq, const float* __restrict__ Wk,
                       const float* __restrict__ Wv, const float* __restrict__ Wo,
                       u16* __restrict__ xb, u16* __restrict__ wtqkv,
                       u16* __restrict__ wto, float* __restrict__ bias) {
  const int tid = threadIdx.x;
  const int bid = blockIdx.x;
  if (bid < 4096) {
    __shared__ float t[32][33];
    const int wi = bid >> 10, inner = bid & 1023;
    const float* W = (wi == 0) ? Wq : (wi == 1) ? Wk : (wi == 2) ? Wv : Wo;
    u16* Wt = (wi == 3) ? wto : wtqkv + (size_t)wi * 1024 * 1024;
    const int tx = tid & 31, ty = tid >> 5;
    const int c0 = (inner & 31) * 32, r0 = (inner >> 5) * 32;
#pragma unroll
    for (int i = 0; i < 4; ++i)
      t[ty + i * 8][tx] = W[(size_t)(r0 + ty + i * 8) * 1024 + c0 + tx];
    __syncthreads();
#pragma unroll
    for (int i = 0; i < 4; ++i)
      Wt[(size_t)(c0 + ty + i * 8) * 1024 + r0 + tx] = f2bf(t[tx][ty + i * 8]);
  } else if (bid < 8192) {
    int i = ((bid - 4096) * 256 + tid) * 4;
    f32x4 v = *(const f32x4*)(x + i);
    u16x4 o;
#pragma unroll
    for (int j = 0; j < 4; ++j) o[j] = f2bf(v[j]);
    *(u16x4*)(xb + i) = o;
  } else {
    int i = (bid - 8192) * 256 + tid;  // 0..3071
    float v = (i < 1024) ? bq[i] : (i < 2048) ? bk[i - 1024] : bv[i - 2048];
    bias[i] = v;
  }
}

// ---------------- GEMM: C[M][ldc] = A[M][1024] * Bt[N][1024]^T + bias ----------------
// 128x128 tile, BK=32, 4 waves (2x2), each wave 64x64 = 4x4 fragments of 16x16x32.
// When vtp != nullptr: n-columns >= 2048 (the V projection) are written TRANSPOSED
// to vtp[(b*16+h)*64+d][s] instead of to C (attn only reads V via vt).

template <typename CT>
__launch_bounds__(256) __global__
void k_gemm_bt(const u16* __restrict__ A, const u16* __restrict__ Bt,
               const float* __restrict__ bias, CT* __restrict__ C, int ldc,
               u16* __restrict__ vtp) {
  __shared__ __align__(16) u16 lA[128 * 32];
  __shared__ __align__(16) u16 lB[128 * 32];
  __shared__ __align__(16) float ep[4][16][68];
  const int tid = threadIdx.x;
  const int w = tid >> 6, lane = tid & 63, g = lane >> 4, n16 = lane & 15;
  const int wm = w >> 1, wn = w & 1;
  const int m0 = blockIdx.y * 128, n0 = blockIdx.x * 128;

  f32x4 acc[4][4] = {};
  for (int k0 = 0; k0 < 1024; k0 += 32) {
    __syncthreads();
#pragma unroll
    for (int r = 0; r < 2; ++r) {
      int c = r * 256 + tid;
      load_lds16(A + (size_t)(m0 + (c >> 2)) * 1024 + k0 + (c & 3) * 8, &lA[c * 8]);
      load_lds16(Bt + (size_t)(n0 + (c >> 2)) * 1024 + k0 + (c & 3) * 8, &lB[c * 8]);
    }
    __syncthreads();
    bf16x8 af[4], bfr[4];
#pragma unroll
    for (int i = 0; i < 4; ++i)
      af[i] = *(const bf16x8*)&lA[(wm * 64 + i * 16 + n16) * 32 + g * 8];
#pragma unroll
    for (int j = 0; j < 4; ++j)
      bfr[j] = *(const bf16x8*)&lB[(wn * 64 + j * 16 + n16) * 32 + g * 8];
#pragma unroll
    for (int i = 0; i < 4; ++i)
#pragma unroll
      for (int j = 0; j < 4; ++j)
        acc[i][j] = __builtin_amdgcn_mfma_f32_16x16x32_bf16(af[i], bfr[j], acc[i][j], 0, 0, 0);
  }

  const int m_base = m0 + wm * 64, n_base = n0 + wn * 64;
  bool vmode = false;
  if constexpr (sizeof(CT) == 2) vmode = (vtp != nullptr) && (n_base >= 2048);

#pragma unroll
  for (int i = 0; i < 4; ++i) {
#pragma unroll
    for (int j = 0; j < 4; ++j) {
      float bv = bias[n_base + j * 16 + n16];
#pragma unroll
      for (int jj = 0; jj < 4; ++jj)
        ep[w][g * 4 + jj][j * 16 + n16] = acc[i][j][jj] + bv;
    }
    asm volatile("s_waitcnt lgkmcnt(0)" ::: "memory");
    if (vmode) {
      // transposed V store: lane = d (0..63), 16 s-values from ep column `lane`
      const int hd = n_base - 2048;          // 64-aligned
      const int head = hd >> 6;
      const int m_row0 = m_base + i * 16;    // tile never crosses the b boundary
      const int bb = m_row0 >> 11, s0 = m_row0 & 2047;
      union { u16 a[16]; u32x4 v[2]; } pk;
#pragma unroll
      for (int r = 0; r < 16; ++r) pk.a[r] = f2bf(ep[w][r][lane]);
      size_t vrow = ((size_t)(bb * 16 + head) * 64 + lane) * 2048 + s0;
      *(u32x4*)(vtp + vrow) = pk.v[0];
      *(u32x4*)(vtp + vrow + 8) = pk.v[1];
    } else {
#pragma unroll
      for (int p = 0; p < 4; ++p) {
        int row = p * 4 + g;
        f32x4 v = *(const f32x4*)&ep[w][row][n16 * 4];
        size_t off = (size_t)(m_base + i * 16 + row) * ldc + n_base + n16 * 4;
        if constexpr (sizeof(CT) == 2) {
          u16x4 o;
#pragma unroll
          for (int q = 0; q < 4; ++q) o[q] = f2bf(v[q]);
          *(u16x4*)(C + off) = o;
        } else {
          *(f32x4*)(C + off) = v;
        }
      }
    }
    asm volatile("s_waitcnt lgkmcnt(0)" ::: "memory");
  }
}

// ---------------- banded attention (block-level LDS staging, phased K->V) ----------------
// block = (b, h, 64-query tile); 4 waves. Staged window = [q0b-128, q0b+192) = 320 keys.
// Phase 1: K[320][64] in LDS (40KB), XOR-swizzled cc^=(r&7) via per-lane global src.
// Phase 2: same buffer becomes V^T[64][320] (40 chunks/row, same swizzle).
// Per-wave scores stay in registers (swapped-operand QK^T, P lands in PV A-frag order).

__launch_bounds__(256, 3) __global__
void k_attn(const u16* __restrict__ qkv, const u16* __restrict__ vt,
            u16* __restrict__ attn) {
  __shared__ __align__(16) u16 KV[20480];        // 40KB: K then V^T
  __shared__ __align__(16) u16 Ostg[4][16][64];  // 8KB output staging
  const int tid = threadIdx.x;
  const int w = tid >> 6, lane = tid & 63, g = lane >> 4, n16 = lane & 15;
  const int bid = (blockIdx.x & 7) * 128 + (blockIdx.x >> 3);
  const int qt = bid & 31, h = (bid >> 5) & 15, b = bid >> 9;
  const int q0b = qt * 64;
  const int kvb = q0b - 128;
  const int q0 = q0b + w * 16;
  const int kv0 = q0 - 128;
  const int q = q0 + n16;
  const int bh = b * 16 + h;

  // ---- stage K: LDS chunk (r, cc) holds K[kvb+r][(cc^(r&7))*8 .. +8)
  {
    const u16* kpart = qkv + (size_t)b * 2048 * 3072 + 1024 + h * 64;
#pragma unroll
    for (int i = 0; i < 10; ++i) {
      int c = i * 256 + tid;
      int r = c >> 3, cc = c & 7;
      int srcr = min(max(kvb + r, 0), 2047);
      load_lds16(kpart + (size_t)srcr * 3072 + (cc ^ (r & 7)) * 8, &KV[c * 8]);
    }
  }

  const size_t rowQ = (size_t)(b * 2048 + q) * 3072 + h * 64;
  bf16x8 qf0 = *(const bf16x8*)(qkv + rowQ + g * 8);
  bf16x8 qf1 = *(const bf16x8*)(qkv + rowQ + 32 + g * 8);
  __syncthreads();

  // ---- QK^T from LDS: sv[t][jj] = S[key][q], key = kv0+32(t>>1)+4(t&1)+8g+jj
  const int kbase = 8 * (n16 >> 2) + (n16 & 3);
  const int wrel = 16 * w;
  f32x4 sv[18];
#pragma unroll
  for (int t = 0; t < 18; ++t) {
    int kr = wrel + 32 * (t >> 1) + 4 * (t & 1) + kbase;
    int krl = min(kr, 319);
    int p = krl & 7;
    const u16* kp = &KV[krl * 64];
    bf16x8 kf0 = *(const bf16x8*)(kp + (g ^ p) * 8);
    bf16x8 kf1 = *(const bf16x8*)(kp + ((g + 4) ^ p) * 8);
    f32x4 s = {0.f, 0.f, 0.f, 0.f};
    s = __builtin_amdgcn_mfma_f32_16x16x32_bf16(kf0, qf0, s, 0, 0, 0);
    s = __builtin_amdgcn_mfma_f32_16x16x32_bf16(kf1, qf1, s, 0, 0, 0);
    sv[t] = s;
  }
  __syncthreads();  // all waves done reading K region

  // ---- stage V^T into same buffer (async); softmax hides the latency
  {
    const u16* vpart = vt + (size_t)bh * 64 * 2048;
#pragma unroll
    for (int i = 0; i < 10; ++i) {
      int c = i * 256 + tid;
      int d = c / 40, cc = c - d * 40;
      int j = cc ^ (d & 7);
      int srck = min(max(kvb + j * 8, 0), 2040);
      load_lds16(vpart + (size_t)d * 2048 + srck, &KV[c * 8]);
    }
  }

  // ---- band mask
  const float NEG = -__builtin_inff();
#pragma unroll
  for (int t = 0; t < 18; ++t) {
    int kb = kv0 + 32 * (t >> 1) + 4 * (t & 1) + 8 * g;
#pragma unroll
    for (int jj = 0; jj < 4; ++jj) {
      int k = kb + jj;
      bool ok = ((unsigned)k < 2048u) && ((unsigned)(q - k + 128) <= 256u);
      sv[t][jj] = ok ? sv[t][jj] : NEG;
    }
  }

  // ---- softmax for query q
  float mx = NEG;
#pragma unroll
  for (int t = 0; t < 18; ++t)
    mx = fmaxf(mx, fmaxf(fmaxf(sv[t][0], sv[t][1]), fmaxf(sv[t][2], sv[t][3])));
  mx = fmaxf(mx, __shfl_xor(mx, 16));
  mx = fmaxf(mx, __shfl_xor(mx, 32));

  const float c = 0.04508422017f;  // log2(e) / sqrt(1024)
  const float nmc = -mx * c;
  float sum = 0.f;
#pragma unroll
  for (int t = 0; t < 18; ++t)
#pragma unroll
    for (int jj = 0; jj < 4; ++jj) {
      float p = exp2f(fmaf(sv[t][jj], c, nmc));
      sv[t][jj] = p;
      sum += p;
    }
  sum += __shfl_xor(sum, 16);
  sum += __shfl_xor(sum, 32);
  const float inv = 1.f / sum;

  __syncthreads();  // V^T staged (barrier drains vmcnt), all waves past mask

  // ---- PV from LDS V^T; P already lane-local in A-frag order
  f32x4 oacc[4] = {};
#pragma unroll
  for (int s = 0; s < 9; ++s) {
    union { u32 u[4]; bf16x8 v; } paf;
    paf.u[0] = cvt_pk_bf16(sv[2 * s][0], sv[2 * s][1]);
    paf.u[1] = cvt_pk_bf16(sv[2 * s][2], sv[2 * s][3]);
    paf.u[2] = cvt_pk_bf16(sv[2 * s + 1][0], sv[2 * s + 1][1]);
    paf.u[3] = cvt_pk_bf16(sv[2 * s + 1][2], sv[2 * s + 1][3]);
    int jc = min(2 * w + 4 * s + g, 39);
#pragma unroll
    for (int dt = 0; dt < 4; ++dt) {
      int d = dt * 16 + n16;
      bf16x8 vf = *(const bf16x8*)&KV[d * 320 + (jc ^ (d & 7)) * 8];
      oacc[dt] = __builtin_amdgcn_mfma_f32_16x16x32_bf16(paf.v, vf, oacc[dt], 0, 0, 0);
    }
  }

  float rs[4];
#pragma unroll
  for (int jj = 0; jj < 4; ++jj) rs[jj] = __shfl(inv, 4 * g + jj);

#pragma unroll
  for (int dt = 0; dt < 4; ++dt)
#pragma unroll
    for (int jj = 0; jj < 4; ++jj)
      Ostg[w][g * 4 + jj][dt * 16 + n16] = f2bf(oacc[dt][jj] * rs[jj]);
  asm volatile("s_waitcnt lgkmcnt(0)" ::: "memory");
#pragma unroll
  for (int p = 0; p < 2; ++p) {
    int fl = p * 512 + lane * 8;
    int row = fl >> 6, col = fl & 63;
    u32x4 v = *(const u32x4*)&Ostg[w][row][col];
    *(u32x4*)(attn + (size_t)(b * 2048 + q0 + row) * 1024 + h * 64 + col) = v;
  }
}

// ---------------- launch ----------------

extern "C" void kernel_launch(void* const* d_in, const int* in_sizes, int n_in,
                              void* d_out, int out_size, void* d_ws, size_t ws_size,
                              hipStream_t stream) {
  const float* x  = (const float*)d_in[0];
  const float* Wq = (const float*)d_in[1];
  const float* bq = (const float*)d_in[2];
  const float* Wk = (const float*)d_in[3];
  const float* bk = (const float*)d_in[4];
  const float* Wv = (const float*)d_in[5];
  const float* bv = (const float*)d_in[6];
  const float* Wo = (const float*)d_in[7];
  const float* bo = (const float*)d_in[8];

  char* ws = (char*)d_ws;
  const size_t MB = 1ull << 20;
  u16*   xb    = (u16*)(ws + 0);         // 8 MB   (dead after QKV GEMM)
  u16*   wtqkv = (u16*)(ws + 8 * MB);    // 6 MB
  u16*   wto   = (u16*)(ws + 14 * MB);   // 2 MB
  float* bias  = (float*)(ws + 16 * MB); // 12 KB
  u16*   qkvb  = (u16*)(ws + 17 * MB);   // 24 MB (V columns unused)
  u16*   vtb   = (u16*)(ws + 41 * MB);   // 8 MB
  u16*   attnb = (u16*)(ws + 0);         // reuse xb's 8 MB

  k_prep<<<8204, 256, 0, stream>>>(x, bq, bk, bv, Wq, Wk, Wv, Wo,
                                   xb, wtqkv, wto, bias);
  k_gemm_bt<u16><<<dim3(24, 32), 256, 0, stream>>>(xb, wtqkv, bias, qkvb, 3072, vtb);
  k_attn<<<1024, 256, 0, stream>>>(qkvb, vtb, attnb);
  k_gemm_bt<float><<<dim3(8, 32), 256, 0, stream>>>(attnb, wto, bo, (float*)d_out, 1024,
                                                    nullptr);
}